// Round 1
// baseline (1644.139 us; speedup 1.0000x reference)
//
#include <hip/hip_runtime.h>

#define ND 64
#define H1 128
#define H2 64
#define MLP_BLK 128

// Per-atom MLP forward + backward.
//   h1 = tanh(x@W1+b1); h2 = tanh(h1@W2+b2); e = h2@W3+b3
//   dz2 = W3 * (1-h2^2); dh1 = W2@dz2; dz1 = dh1*(1-h1^2); dEdD = W1@dz1
// Thread-per-atom. Weights are wave-uniform -> scalar loads. h1 needs
// dynamic indexing in phases 2/3 -> per-thread LDS column (lane-stride-1,
// 2-way bank aliasing = free on gfx950).
__global__ __launch_bounds__(MLP_BLK) void mlp_kernel(
    const float* __restrict__ x, const int* __restrict__ indices,
    const float* __restrict__ W1, const float* __restrict__ b1,
    const float* __restrict__ W2, const float* __restrict__ b2,
    const float* __restrict__ W3, const float* __restrict__ b3,
    float* __restrict__ energy, float* __restrict__ dEdD, int natoms)
{
    __shared__ float h1s[H1 * MLP_BLK];   // 64 KB
    const int t = threadIdx.x;
    const int i = blockIdx.x * MLP_BLK + t;
    if (i >= natoms) return;

    // ---- phase 1: h1 = tanh(x @ W1 + b1), j unrolled (const reg index)
    float h1[H1];
    #pragma unroll
    for (int j = 0; j < H1; ++j) h1[j] = b1[j];
    for (int k = 0; k < ND; ++k) {
        float xk = x[(size_t)i * ND + k];
        const float* w = W1 + k * H1;
        #pragma unroll
        for (int j = 0; j < H1; ++j) h1[j] = fmaf(xk, w[j], h1[j]);
    }
    #pragma unroll
    for (int j = 0; j < H1; ++j) {
        h1s[j * MLP_BLK + t] = tanhf(h1[j]);
    }

    // ---- phase 2: h2 = tanh(h1 @ W2 + b2); e = h2@W3+b3; dz2 in regs
    float h2[H2];
    #pragma unroll
    for (int j = 0; j < H2; ++j) h2[j] = b2[j];
    for (int k = 0; k < H1; ++k) {
        float hk = h1s[k * MLP_BLK + t];
        const float* w = W2 + k * H2;
        #pragma unroll
        for (int j = 0; j < H2; ++j) h2[j] = fmaf(hk, w[j], h2[j]);
    }
    float e = b3[0];
    float dz2[H2];
    #pragma unroll
    for (int j = 0; j < H2; ++j) {
        float v = tanhf(h2[j]);
        float w3 = W3[j];
        e = fmaf(v, w3, e);
        dz2[j] = w3 * (1.0f - v * v);
    }
    atomicAdd(&energy[indices[i]], e);

    // ---- phase 3: dEdD[k] = sum_j dz1_j * W1[k][j], fused over j
    float d[ND];
    #pragma unroll
    for (int k = 0; k < ND; ++k) d[k] = 0.0f;
    for (int j = 0; j < H1; ++j) {
        const float* w2r = W2 + j * H2;       // W2[j][:]
        float dh1 = 0.0f;
        #pragma unroll
        for (int k = 0; k < H2; ++k) dh1 = fmaf(dz2[k], w2r[k], dh1);
        float h = h1s[j * MLP_BLK + t];
        float dz1 = dh1 * (1.0f - h * h);
        const float* w1c = W1 + j;            // W1[k][j] = W1[k*H1+j]
        #pragma unroll
        for (int k = 0; k < ND; ++k) d[k] = fmaf(dz1, w1c[k * H1], d[k]);
    }
    float4* outp = (float4*)(dEdD + (size_t)i * ND);
    #pragma unroll
    for (int k = 0; k < ND; k += 4) {
        float4 v = {d[k], d[k+1], d[k+2], d[k+3]};
        outp[k / 4] = v;
    }
}

// Thread-per-pair: reads its contiguous 768 B of xd (3 rows x 64 f32) via
// float4, gathers the g row (dEdD[neigh], L2/L3-resident), 3 thread-local
// dots, 3 device-scope atomics into the interleaved force output.
__global__ __launch_bounds__(256) void pairs_kernel(
    const float* __restrict__ xd, const int* __restrict__ xd_indx,
    const int* __restrict__ unique_j, const float* __restrict__ dEdD,
    float* __restrict__ forces, int npairs)
{
    const int p = blockIdx.x * 256 + threadIdx.x;
    if (p >= npairs) return;
    const int neigh = xd_indx[6 * (size_t)p];        // xd_indx[3p][0]
    const float4* g = (const float4*)(dEdD + (size_t)neigh * ND);
    const float4* a = (const float4*)(xd + (size_t)p * (3 * ND));
    float sx = 0.f, sy = 0.f, sz = 0.f;
    #pragma unroll 4
    for (int tt = 0; tt < 16; ++tt) {
        float4 gv = g[tt];
        float4 v0 = a[tt];
        float4 v1 = a[tt + 16];
        float4 v2 = a[tt + 32];
        sx += v0.x * gv.x + v0.y * gv.y + v0.z * gv.z + v0.w * gv.w;
        sy += v1.x * gv.x + v1.y * gv.y + v1.z * gv.z + v1.w * gv.w;
        sz += v2.x * gv.x + v2.y * gv.y + v2.z * gv.z + v2.w * gv.w;
    }
    const int uj0 = unique_j[3 * (size_t)p];
    const int uj1 = unique_j[3 * (size_t)p + 1];
    const int uj2 = unique_j[3 * (size_t)p + 2];
    atomicAdd(&forces[3 * uj0 + 0], -sx);
    atomicAdd(&forces[3 * uj1 + 1], -sy);
    atomicAdd(&forces[3 * uj2 + 2], -sz);
}

extern "C" void kernel_launch(void* const* d_in, const int* in_sizes, int n_in,
                              void* d_out, int out_size, void* d_ws, size_t ws_size,
                              hipStream_t stream)
{
    const float* x        = (const float*)d_in[0];
    const float* xd       = (const float*)d_in[1];
    const int*   indices  = (const int*)d_in[2];
    // d_in[3] atoms_per_structure: only defines n_struct
    const int*   xd_indx  = (const int*)d_in[4];
    const int*   unique_j = (const int*)d_in[5];
    const float* W1 = (const float*)d_in[6];
    const float* b1 = (const float*)d_in[7];
    const float* W2 = (const float*)d_in[8];
    const float* b2 = (const float*)d_in[9];
    const float* W3 = (const float*)d_in[10];
    const float* b3 = (const float*)d_in[11];

    const int natoms  = in_sizes[0] / ND;   // 50000
    const int nstruct = in_sizes[3];        // 250
    const int npairs  = in_sizes[5] / 3;    // 1e6

    float* out    = (float*)d_out;
    float* energy = out;                    // [nstruct]
    float* forces = out + nstruct;          // [natoms*3], interleaved xyz
    float* dEdD   = (float*)d_ws;           // [natoms*ND] f32 scratch

    // Output is accumulated with atomics -> must start from zero every call
    // (harness re-poisons d_out with 0xAA before each timed launch).
    hipMemsetAsync(d_out, 0, (size_t)out_size * sizeof(float), stream);

    mlp_kernel<<<(natoms + MLP_BLK - 1) / MLP_BLK, MLP_BLK, 0, stream>>>(
        x, indices, W1, b1, W2, b2, W3, b3, energy, dEdD, natoms);

    pairs_kernel<<<(npairs + 255) / 256, 256, 0, stream>>>(
        xd, xd_indx, unique_j, dEdD, forces, npairs);
}

// Round 2
// 1258.569 us; speedup vs baseline: 1.3064x; 1.3064x over previous
//
#include <hip/hip_runtime.h>

#define ND 64
#define H1 128
#define H2 64

// ---------------- K1: t1T[j, i] = tanh(x[i,:] @ W1[:,j] + b1[j]) ------------
// Block = 256 threads = 64 atoms x 4 j-chunks of 32. x tile staged in LDS
// (stride 65 -> 2-way bank aliasing = free). W1 wave-uniform. Output stored
// TRANSPOSED [H1, natoms] so downstream k-loops are lane-coalesced.
__global__ __launch_bounds__(256) void k1_h1(
    const float* __restrict__ x, const float* __restrict__ W1,
    const float* __restrict__ b1, float* __restrict__ t1T, int natoms)
{
    __shared__ float xs[64 * 65];
    const int t = threadIdx.x;
    const size_t xbase = (size_t)blockIdx.x * 64 * ND;
    const size_t xlimit = (size_t)natoms * ND;

    #pragma unroll
    for (int q = 0; q < 4; ++q) {
        int f = q * 1024 + t * 4;            // flat idx in 64x64 tile
        int atom = f >> 6, k = f & 63;
        float4 v = {0.f, 0.f, 0.f, 0.f};
        if (xbase + f < xlimit) v = *(const float4*)(x + xbase + f);
        xs[atom * 65 + k + 0] = v.x;
        xs[atom * 65 + k + 1] = v.y;
        xs[atom * 65 + k + 2] = v.z;
        xs[atom * 65 + k + 3] = v.w;
    }
    __syncthreads();

    const int atom = t & 63;                 // lane -> atom (coalesced)
    const int c = t >> 6;                    // wave -> j-chunk (uniform)
    const int i = blockIdx.x * 64 + atom;

    float acc[32];
    #pragma unroll
    for (int j = 0; j < 32; ++j) acc[j] = b1[c * 32 + j];
    for (int k = 0; k < ND; ++k) {
        float xk = xs[atom * 65 + k];
        const float* w = W1 + k * H1 + c * 32;
        #pragma unroll
        for (int j = 0; j < 32; ++j) acc[j] = fmaf(xk, w[j], acc[j]);
    }
    if (i < natoms) {
        #pragma unroll
        for (int j = 0; j < 32; ++j)
            t1T[(size_t)(c * 32 + j) * natoms + i] = tanhf(acc[j]);
    }
}

// ---------------- K2: fused h2 / energy / dz2 / dEdD ------------------------
// Thread-per-atom; all global reads lane-coalesced (t1T transposed).
__global__ __launch_bounds__(256) void k2_rest(
    const float* __restrict__ t1T, const int* __restrict__ indices,
    const float* __restrict__ W1, const float* __restrict__ W2,
    const float* __restrict__ b2, const float* __restrict__ W3,
    const float* __restrict__ b3, float* __restrict__ energy,
    float* __restrict__ dEdD, int natoms)
{
    const int i = blockIdx.x * 256 + threadIdx.x;
    if (i >= natoms) return;

    // h2 = tanh(t1 @ W2 + b2)
    float h2[H2];
    #pragma unroll
    for (int j = 0; j < H2; ++j) h2[j] = b2[j];
    for (int k = 0; k < H1; ++k) {
        float hk = t1T[(size_t)k * natoms + i];
        const float* w = W2 + k * H2;
        #pragma unroll
        for (int j = 0; j < H2; ++j) h2[j] = fmaf(hk, w[j], h2[j]);
    }
    // e, dz2 = W3 * (1 - h2^2)
    float e = b3[0];
    float dz2[H2];
    #pragma unroll
    for (int j = 0; j < H2; ++j) {
        float v = tanhf(h2[j]);
        float w3 = W3[j];
        e = fmaf(v, w3, e);
        dz2[j] = w3 * (1.0f - v * v);
    }
    atomicAdd(&energy[indices[i]], e);

    // dEdD[k] = sum_j (1 - t1_j^2) * (dz2 . W2[j,:]) * W1[k,j]
    float d[ND];
    #pragma unroll
    for (int k = 0; k < ND; ++k) d[k] = 0.0f;
    for (int j = 0; j < H1; ++j) {
        const float* w2r = W2 + j * H2;
        float dh1 = 0.0f;
        #pragma unroll
        for (int k = 0; k < H2; ++k) dh1 = fmaf(dz2[k], w2r[k], dh1);
        float tj = t1T[(size_t)j * natoms + i];
        float dz1 = dh1 * (1.0f - tj * tj);
        const float* w1c = W1 + j;
        #pragma unroll
        for (int k = 0; k < ND; ++k) d[k] = fmaf(dz1, w1c[k * H1], d[k]);
    }
    float4* outp = (float4*)(dEdD + (size_t)i * ND);
    #pragma unroll
    for (int k = 0; k < ND; k += 4) {
        float4 v = {d[k], d[k + 1], d[k + 2], d[k + 3]};
        outp[k / 4] = v;
    }
}

// ---------------- fallback MLP (small ws): round-1 kernel -------------------
__global__ __launch_bounds__(128) void mlp_fallback(
    const float* __restrict__ x, const int* __restrict__ indices,
    const float* __restrict__ W1, const float* __restrict__ b1,
    const float* __restrict__ W2, const float* __restrict__ b2,
    const float* __restrict__ W3, const float* __restrict__ b3,
    float* __restrict__ energy, float* __restrict__ dEdD, int natoms)
{
    __shared__ float h1s[H1 * 128];
    const int t = threadIdx.x;
    const int i = blockIdx.x * 128 + t;
    if (i >= natoms) return;
    float h1[H1];
    #pragma unroll
    for (int j = 0; j < H1; ++j) h1[j] = b1[j];
    for (int k = 0; k < ND; ++k) {
        float xk = x[(size_t)i * ND + k];
        const float* w = W1 + k * H1;
        #pragma unroll
        for (int j = 0; j < H1; ++j) h1[j] = fmaf(xk, w[j], h1[j]);
    }
    #pragma unroll
    for (int j = 0; j < H1; ++j) h1s[j * 128 + t] = tanhf(h1[j]);
    float h2[H2];
    #pragma unroll
    for (int j = 0; j < H2; ++j) h2[j] = b2[j];
    for (int k = 0; k < H1; ++k) {
        float hk = h1s[k * 128 + t];
        const float* w = W2 + k * H2;
        #pragma unroll
        for (int j = 0; j < H2; ++j) h2[j] = fmaf(hk, w[j], h2[j]);
    }
    float e = b3[0];
    float dz2[H2];
    #pragma unroll
    for (int j = 0; j < H2; ++j) {
        float v = tanhf(h2[j]);
        float w3 = W3[j];
        e = fmaf(v, w3, e);
        dz2[j] = w3 * (1.0f - v * v);
    }
    atomicAdd(&energy[indices[i]], e);
    float d[ND];
    #pragma unroll
    for (int k = 0; k < ND; ++k) d[k] = 0.0f;
    for (int j = 0; j < H1; ++j) {
        const float* w2r = W2 + j * H2;
        float dh1 = 0.0f;
        #pragma unroll
        for (int k = 0; k < H2; ++k) dh1 = fmaf(dz2[k], w2r[k], dh1);
        float h = h1s[j * 128 + t];
        float dz1 = dh1 * (1.0f - h * h);
        const float* w1c = W1 + j;
        #pragma unroll
        for (int k = 0; k < ND; ++k) d[k] = fmaf(dz1, w1c[k * H1], d[k]);
    }
    float4* outp = (float4*)(dEdD + (size_t)i * ND);
    #pragma unroll
    for (int k = 0; k < ND; k += 4) {
        float4 v = {d[k], d[k + 1], d[k + 2], d[k + 3]};
        outp[k / 4] = v;
    }
}

// ---------------- pairs: 16 lanes per pair ----------------------------------
// Lane l of a 16-lane cluster loads float4 #l of each of the pair's 3 xd rows
// and of the gathered g row -> 16 cache lines per instruction instead of 64.
// Butterfly shfl_xor reduce (masks 8..1 stay inside the cluster); lanes 0/1/2
// issue the 3 force atomics.
__global__ __launch_bounds__(256) void pairs16_kernel(
    const float* __restrict__ xd, const int* __restrict__ xd_indx,
    const int* __restrict__ unique_j, const float* __restrict__ dEdD,
    float* __restrict__ forces, int npairs)
{
    const size_t tid = (size_t)blockIdx.x * 256 + threadIdx.x;
    const int p = (int)(tid >> 4);
    const int sub = (int)(tid & 15);
    if (p >= npairs) return;

    const int neigh = xd_indx[6 * (size_t)p];
    const float4* g4 = (const float4*)(dEdD + (size_t)neigh * ND);
    const float4* a4 = (const float4*)(xd + (size_t)p * (3 * ND));

    float4 gv = g4[sub];
    float4 v0 = a4[sub];
    float4 v1 = a4[sub + 16];
    float4 v2 = a4[sub + 32];

    float sx = v0.x * gv.x + v0.y * gv.y + v0.z * gv.z + v0.w * gv.w;
    float sy = v1.x * gv.x + v1.y * gv.y + v1.z * gv.z + v1.w * gv.w;
    float sz = v2.x * gv.x + v2.y * gv.y + v2.z * gv.z + v2.w * gv.w;

    #pragma unroll
    for (int m = 8; m >= 1; m >>= 1) {
        sx += __shfl_xor(sx, m);
        sy += __shfl_xor(sy, m);
        sz += __shfl_xor(sz, m);
    }
    if (sub < 3) {
        float val = (sub == 0) ? sx : ((sub == 1) ? sy : sz);
        int uj = unique_j[3 * (size_t)p + sub];
        atomicAdd(&forces[3 * uj + sub], -val);
    }
}

extern "C" void kernel_launch(void* const* d_in, const int* in_sizes, int n_in,
                              void* d_out, int out_size, void* d_ws, size_t ws_size,
                              hipStream_t stream)
{
    const float* x        = (const float*)d_in[0];
    const float* xd       = (const float*)d_in[1];
    const int*   indices  = (const int*)d_in[2];
    const int*   xd_indx  = (const int*)d_in[4];
    const int*   unique_j = (const int*)d_in[5];
    const float* W1 = (const float*)d_in[6];
    const float* b1 = (const float*)d_in[7];
    const float* W2 = (const float*)d_in[8];
    const float* b2 = (const float*)d_in[9];
    const float* W3 = (const float*)d_in[10];
    const float* b3 = (const float*)d_in[11];

    const int natoms  = in_sizes[0] / ND;   // 50000
    const int nstruct = in_sizes[3];        // 250
    const int npairs  = in_sizes[5] / 3;    // 1e6

    float* out    = (float*)d_out;
    float* energy = out;
    float* forces = out + nstruct;

    float* dEdD = (float*)d_ws;                      // [natoms*64]  12.8 MB
    float* t1T  = (float*)d_ws + (size_t)natoms * ND; // [128*natoms] 25.6 MB

    const size_t need = (size_t)natoms * (ND + H1) * sizeof(float);

    hipMemsetAsync(d_out, 0, (size_t)out_size * sizeof(float), stream);

    if (ws_size >= need) {
        k1_h1<<<(natoms + 63) / 64, 256, 0, stream>>>(x, W1, b1, t1T, natoms);
        k2_rest<<<(natoms + 255) / 256, 256, 0, stream>>>(
            t1T, indices, W1, W2, b2, W3, b3, energy, dEdD, natoms);
    } else {
        mlp_fallback<<<(natoms + 127) / 128, 128, 0, stream>>>(
            x, indices, W1, b1, W2, b2, W3, b3, energy, dEdD, natoms);
    }

    pairs16_kernel<<<(npairs * 16 + 255) / 256, 256, 0, stream>>>(
        xd, xd_indx, unique_j, dEdD, forces, npairs);
}